// Round 12
// baseline (119.662 us; speedup 1.0000x reference)
//
#include <hip/hip_runtime.h>

// LIF integrate-fire-reset scan over T.
// inputs: [B=32, T=2048, N=1024] f32; thresh: [N] f32; out: [B, T, N] f32.
//
// R12 = R11 (scalar chain/lane, in-place circular register pipeline D=32,
// PLAIN cached loads — the R11 win: input is exactly L3-sized, 50% of
// fetches served by Infinity Cache, 105.7 -> 82.0 us) with ONE change:
// stores are now PLAIN too (write-back cached) instead of nontemporal.
//
// Why: loads and stores share the per-wave 63-slot vmcnt budget (D=32 sits
// exactly at 63). nt stores likely complete only at the memory controller
// (~1.6 us loaded round-trip), so each store hogs a slot ~10x longer than a
// plain store acked by L2 write-back (~200 cy). Plain stores recycle slots
// fast -> more of the budget holds loads in flight. Risk: write-allocate
// evicts the input from L3 (FETCH rises). A/B with asymmetric outcomes:
//   slot-recycling dominates -> ~70 us; eviction dominates -> ~100 us,
//   revert to R11 and declare roofline.

constexpr int T_STEPS = 2048;
constexpr int N_COLS  = 1024;
constexpr int D       = 32;   // pipeline depth (T_STEPS % D == 0)

__global__ __launch_bounds__(64, 1)
void lif_scan_kernel(const float* __restrict__ x,
                     const float* __restrict__ thresh,
                     float* __restrict__ out)
{
    const int gid = blockIdx.x * blockDim.x + threadIdx.x;   // 0 .. B*N-1
    const int b   = gid >> 10;          // / N_COLS
    const int n   = gid & (N_COLS - 1); // % N_COLS

    const float thr = thresh[n];

    const size_t base = (size_t)b * T_STEPS * N_COLS + n;
    const float* __restrict__ p = x   + base;
    float*       __restrict__ q = out + base;

    float buf[D];

    // prologue: prime the pipeline (plain cached loads)
#pragma unroll
    for (int i = 0; i < D; ++i)
        buf[i] = p[(size_t)i * N_COLS];

    float acc = 0.0f;

    // steady state: per element, consume slot i then refill it D ahead.
    for (int t0 = 0; t0 < T_STEPS - D; t0 += D) {
#pragma unroll
        for (int i = 0; i < D; ++i) {
            const float v = buf[i];
            buf[i] = p[(size_t)(t0 + D + i) * N_COLS];
            acc += v;
            const float o = (acc > thr) ? acc : 0.0f;
            acc -= o;   // reset fired neuron to 0
            q[(size_t)(t0 + i) * N_COLS] = o;
        }
    }

    // epilogue: drain the last D elements (no further loads)
#pragma unroll
    for (int i = 0; i < D; ++i) {
        acc += buf[i];
        const float o = (acc > thr) ? acc : 0.0f;
        acc -= o;
        q[(size_t)(T_STEPS - D + i) * N_COLS] = o;
    }
}

extern "C" void kernel_launch(void* const* d_in, const int* in_sizes, int n_in,
                              void* d_out, int out_size, void* d_ws, size_t ws_size,
                              hipStream_t stream)
{
    const float* x      = (const float*)d_in[0];
    const float* thresh = (const float*)d_in[1];
    float*       out    = (float*)d_out;

    const int total = in_sizes[0] / T_STEPS;   // B * N chains
    (void)out_size; (void)d_ws; (void)ws_size; (void)n_in;

    const int block = 64;
    const int grid  = (total + block - 1) / block;   // 512 blocks

    hipLaunchKernelGGL(lif_scan_kernel, dim3(grid), dim3(block), 0, stream,
                       x, thresh, out);
}

// Round 13
// 81.287 us; speedup vs baseline: 1.4721x; 1.4721x over previous
//
#include <hip/hip_runtime.h>

// LIF integrate-fire-reset scan over T.
// inputs: [B=32, T=2048, N=1024] f32; thresh: [N] f32; out: [B, T, N] f32.
//
// R13 = R11 revert (the measured best: 82.0 us, logical 6.55 TB/s, above
// the 6.29 TB/s D2D copy ceiling thanks to ~50% L3 hits on the re-read
// input). R12's plain stores regressed to 119.7 us — write-allocate evicts
// the input from Infinity Cache; confirmed eviction >> slot-recycling.
//
// Structure: one lane per (b,n) chain (512 waves = 2/CU, the max the
// problem's 32768 chains allow), coalesced 256 B/wave per timestep,
// in-place circular register pipeline D=32 (vmcnt budget exactly 63:
// 31 younger loads + 32 stores at each use-wait).
//   - loads PLAIN  (input is exactly L3-sized; caching -> 50% fetch cut)
//   - stores NT    (no-allocate: output stream must not evict the input)
//
// Ledger of falsified levers: deeper in-flight via LDS (R8 null), float4
// width (R9 worse), XCD remap (R10 worse), plain stores (R12 much worse).
// Remaining gap to the ~77 us fabric bound (537 MB @ ~7 TB/s) is ~5%.

constexpr int T_STEPS = 2048;
constexpr int N_COLS  = 1024;
constexpr int D       = 32;   // pipeline depth (T_STEPS % D == 0)

__global__ __launch_bounds__(64, 1)
void lif_scan_kernel(const float* __restrict__ x,
                     const float* __restrict__ thresh,
                     float* __restrict__ out)
{
    const int gid = blockIdx.x * blockDim.x + threadIdx.x;   // 0 .. B*N-1
    const int b   = gid >> 10;          // / N_COLS
    const int n   = gid & (N_COLS - 1); // % N_COLS

    const float thr = thresh[n];

    const size_t base = (size_t)b * T_STEPS * N_COLS + n;
    const float* __restrict__ p = x   + base;
    float*       __restrict__ q = out + base;

    float buf[D];

    // prologue: prime the pipeline (plain cached loads)
#pragma unroll
    for (int i = 0; i < D; ++i)
        buf[i] = p[(size_t)i * N_COLS];

    float acc = 0.0f;

    // steady state: per element, consume slot i then refill it D ahead.
    for (int t0 = 0; t0 < T_STEPS - D; t0 += D) {
#pragma unroll
        for (int i = 0; i < D; ++i) {
            const float v = buf[i];
            buf[i] = p[(size_t)(t0 + D + i) * N_COLS];
            acc += v;
            const float o = (acc > thr) ? acc : 0.0f;
            acc -= o;   // reset fired neuron to 0
            __builtin_nontemporal_store(o, &q[(size_t)(t0 + i) * N_COLS]);
        }
    }

    // epilogue: drain the last D elements (no further loads)
#pragma unroll
    for (int i = 0; i < D; ++i) {
        acc += buf[i];
        const float o = (acc > thr) ? acc : 0.0f;
        acc -= o;
        __builtin_nontemporal_store(o, &q[(size_t)(T_STEPS - D + i) * N_COLS]);
    }
}

extern "C" void kernel_launch(void* const* d_in, const int* in_sizes, int n_in,
                              void* d_out, int out_size, void* d_ws, size_t ws_size,
                              hipStream_t stream)
{
    const float* x      = (const float*)d_in[0];
    const float* thresh = (const float*)d_in[1];
    float*       out    = (float*)d_out;

    const int total = in_sizes[0] / T_STEPS;   // B * N chains
    (void)out_size; (void)d_ws; (void)ws_size; (void)n_in;

    const int block = 64;
    const int grid  = (total + block - 1) / block;   // 512 blocks

    hipLaunchKernelGGL(lif_scan_kernel, dim3(grid), dim3(block), 0, stream,
                       x, thresh, out);
}